// Round 9
// baseline (155.408 us; speedup 1.0000x reference)
//
#include <hip/hip_runtime.h>
#include <hip/hip_bf16.h>
#include <cstdint>

#define NDIM 128
#define KCLAMP 10.0f

using bf16x8 = __attribute__((ext_vector_type(8))) short;
using f32x4  = __attribute__((ext_vector_type(4))) float;
using f32x2  = __attribute__((ext_vector_type(2))) float;

__device__ __forceinline__ uint16_t f2bf(float f) {
    uint32_t u = __float_as_uint(f);
    uint32_t r = (u + 0x7fffu + ((u >> 16) & 1u)) >> 16;   // RNE
    return (uint16_t)r;
}
__device__ __forceinline__ float bf_lo(uint32_t v) { return __uint_as_float(v << 16); }
__device__ __forceinline__ float bf_hi(uint32_t v) { return __uint_as_float(v & 0xffff0000u); }

// ---------------- prep: wfrag + rowptr in one launch ----------------
// wfrag[((n*4+s)*64+lane)*8+i] = bf16(W[k][col]), k=s*32+8*(lane>>4)+i, col=n*16+(lane&15)
__global__ void k_prep(const float* __restrict__ W, uint16_t* __restrict__ wfrag,
                       const int* __restrict__ sdst, int E,
                       int* __restrict__ row_start, int ndst, int wfBlocks) {
    int b = blockIdx.x;
    int tid = threadIdx.x;
    if (b < wfBlocks) {
        int t = b * 256 + tid;
        if (t >= NDIM * NDIM) return;
        int i    = t & 7;
        int lane = (t >> 3) & 63;
        int s    = (t >> 9) & 3;
        int n    = t >> 11;
        int k    = s * 32 + 8 * (lane >> 4) + i;
        int col  = n * 16 + (lane & 15);
        wfrag[t] = f2bf(W[k * NDIM + col]);
    } else {
        int d = (b - wfBlocks) * 256 + tid;     // lower_bound(sdst, d)
        if (d > ndst) return;
        int lo = 0, hi = E;
        while (lo < hi) {
            int mid = (lo + hi) >> 1;
            if (sdst[mid] < d) lo = mid + 1; else hi = mid;
        }
        row_start[d] = lo;
    }
}

// ---------------- k1: trans = bf16((h * norm_src) @ W), slice-major layout ----------------
// trans[s_col][row][16]: element (row, col) stored at trans[(col/16)*nsrc*16 + row*16 + col%16]
__global__ __launch_bounds__(256) void k1_gemm(
        const float* __restrict__ h, const int* __restrict__ odeg,
        const uint16_t* __restrict__ wfrag, uint16_t* __restrict__ trans,
        int M, int nsrc) {
    __shared__ uint16_t Ws[NDIM * NDIM];     // 32 KB, B-frag layout
    int tx = threadIdx.x;
    for (int i = tx; i < NDIM * NDIM / 8; i += 256)
        ((int4*)Ws)[i] = ((const int4*)wfrag)[i];
    __syncthreads();

    int wave = tx >> 6, lane = tx & 63;
    int g = lane >> 4;
    int r0 = blockIdx.x * 64 + wave * 16;
    int arow = r0 + (lane & 15);
    if (arow >= M) arow = M - 1;             // clamp loads; stores predicated
    float nrm = rsqrtf(fmaxf((float)odeg[arow], 1.0f));
    const float4* Arow = (const float4*)(h + (size_t)arow * NDIM);

    f32x4 acc[8];
#pragma unroll
    for (int n = 0; n < 8; ++n) acc[n] = (f32x4){0.f, 0.f, 0.f, 0.f};

#pragma unroll
    for (int s = 0; s < 4; ++s) {
        float4 a0 = Arow[s * 8 + g * 2];     // k = s*32+g*8 .. +3
        float4 a1 = Arow[s * 8 + g * 2 + 1]; // k = s*32+g*8+4 .. +7
        bf16x8 af;
        af[0] = (short)f2bf(a0.x * nrm);
        af[1] = (short)f2bf(a0.y * nrm);
        af[2] = (short)f2bf(a0.z * nrm);
        af[3] = (short)f2bf(a0.w * nrm);
        af[4] = (short)f2bf(a1.x * nrm);
        af[5] = (short)f2bf(a1.y * nrm);
        af[6] = (short)f2bf(a1.z * nrm);
        af[7] = (short)f2bf(a1.w * nrm);
#pragma unroll
        for (int n = 0; n < 8; ++n) {
            bf16x8 bfr = *(const bf16x8*)(Ws + (((n * 4 + s) * 64 + lane) << 3));
            acc[n] = __builtin_amdgcn_mfma_f32_16x16x32_bf16(af, bfr, acc[n], 0, 0, 0);
        }
    }

    int colL = lane & 15;
    int rowbase = r0 + g * 4;
#pragma unroll
    for (int n = 0; n < 8; ++n) {           // n == column slice index
        uint16_t* tslice = trans + (size_t)n * nsrc * 16;
#pragma unroll
        for (int r = 0; r < 4; ++r) {
            int row = rowbase + r;
            if (row < M)
                tslice[(size_t)row * 16 + colL] = f2bf(acc[n][r]);
        }
    }
}

// ---------------- k2: XCD-sliced gather + segment-sum + epilogue ----------------
// Block bid: slice s = bid&7 (== XCD under round-robin dispatch), dst chunk bid>>3.
// Each XCD random-accesses only its 3.2 MB slice -> L2-resident.
// Lane: sub=lane>>3 (dst slot 0..7), eo=(lane>>1)&3 (edge slot), hb=lane&1 (16B half).
// 2-stage pipeline -> 8 edges/dst in flight. Streams use nontemporal hints.
__global__ __launch_bounds__(256) void k2_gather(
        const uint16_t* __restrict__ trans,
        const int* __restrict__ ssrc, const int* __restrict__ row_start,
        const float* __restrict__ bias, const int* __restrict__ ideg,
        float* __restrict__ out, int ndst, int nsrc, int DPB) {
    int bid  = blockIdx.x;
    int s    = bid & 7;
    int chunk = bid >> 3;
    int tx   = threadIdx.x;
    int wave = tx >> 6, lane = tx & 63;
    int sub  = lane >> 3;
    int eo   = (lane >> 1) & 3;
    int hb   = lane & 1;

    const uint16_t* sbase = trans + (size_t)s * nsrc * 16;

    // bias halves for this lane: bias[s*16 + hb*8 .. +7]
    f32x4 bA = *(const f32x4*)(bias + s * 16 + hb * 8);
    f32x4 bB = *(const f32x4*)(bias + s * 16 + hb * 8 + 4);

    int dstart = chunk * DPB;
    int dend   = min(dstart + DPB, ndst);

    for (int db = dstart + wave * 8; db < dend; db += 32) {
        int d = db + sub;
        int valid = (d < dend);
        int sg = 0, e = 0;
        if (valid) {
            sg = __builtin_nontemporal_load(row_start + d);
            e  = __builtin_nontemporal_load(row_start + d + 1);
        }
        int elast = (e > sg) ? (e - 1) : 0;

        float a[8];
#pragma unroll
        for (int k = 0; k < 8; ++k) a[k] = 0.f;

        int pos = sg;
        int i0 = __builtin_nontemporal_load(ssrc + min(pos + eo, elast));
        int i1 = __builtin_nontemporal_load(ssrc + min(pos + 4 + eo, elast));

        while (__any(pos < e)) {
            uint4 v0 = *(const uint4*)(sbase + (size_t)i0 * 16 + hb * 8);
            uint4 v1 = *(const uint4*)(sbase + (size_t)i1 * 16 + hb * 8);
            int np = pos + 8;
            i0 = __builtin_nontemporal_load(ssrc + min(np + eo, elast));
            i1 = __builtin_nontemporal_load(ssrc + min(np + 4 + eo, elast));
            if (pos + eo < e) {
                a[0] += bf_lo(v0.x); a[1] += bf_hi(v0.x);
                a[2] += bf_lo(v0.y); a[3] += bf_hi(v0.y);
                a[4] += bf_lo(v0.z); a[5] += bf_hi(v0.z);
                a[6] += bf_lo(v0.w); a[7] += bf_hi(v0.w);
            }
            if (pos + 4 + eo < e) {
                a[0] += bf_lo(v1.x); a[1] += bf_hi(v1.x);
                a[2] += bf_lo(v1.y); a[3] += bf_hi(v1.y);
                a[4] += bf_lo(v1.z); a[5] += bf_hi(v1.z);
                a[6] += bf_lo(v1.w); a[7] += bf_hi(v1.w);
            }
            pos = np;
        }

        // reduce over the 4 edge slots (lane bits 1..2)
#pragma unroll
        for (int k = 0; k < 8; ++k) {
            a[k] += __shfl_xor(a[k], 2, 64);
            a[k] += __shfl_xor(a[k], 4, 64);
        }

        if (eo == 0 && valid) {
            float nrm = rsqrtf(fminf(fmaxf((float)__builtin_nontemporal_load(ideg + d),
                                           1.0f), KCLAMP));
            f32x4 o0, o1;
            o0[0] = a[0] * nrm + bA[0];
            o0[1] = a[1] * nrm + bA[1];
            o0[2] = a[2] * nrm + bA[2];
            o0[3] = a[3] * nrm + bA[3];
            o1[0] = a[4] * nrm + bB[0];
            o1[1] = a[5] * nrm + bB[1];
            o1[2] = a[6] * nrm + bB[2];
            o1[3] = a[7] * nrm + bB[3];
            float* dst = out + (size_t)d * NDIM + s * 16 + hb * 8;
            __builtin_nontemporal_store(o0, (f32x4*)dst);
            __builtin_nontemporal_store(o1, (f32x4*)(dst + 4));
        }
    }
}

// ---------------- fallbacks (workspace too small) ----------------
__global__ void k_rowptr(const int* __restrict__ sdst, int E,
                         int* __restrict__ row_start, int ndst) {
    int d = blockIdx.x * blockDim.x + threadIdx.x;
    if (d > ndst) return;
    int lo = 0, hi = E;
    while (lo < hi) {
        int mid = (lo + hi) >> 1;
        if (sdst[mid] < d) lo = mid + 1; else hi = mid;
    }
    row_start[d] = lo;
}

__global__ void k_agg_f32(const float* __restrict__ h, const int* __restrict__ odeg,
                          const int* __restrict__ ssrc, const int* __restrict__ row_start,
                          float* __restrict__ agg, int ndst) {
    int gtid = blockIdx.x * blockDim.x + threadIdx.x;
    int wave = gtid >> 6;
    int lane = threadIdx.x & 63;
    int nwaves = (gridDim.x * blockDim.x) >> 6;
    for (int d = wave; d < ndst; d += nwaves) {
        int s = row_start[d], e = row_start[d + 1];
        float a0 = 0.f, a1 = 0.f;
        for (int i = s; i < e; i++) {
            int s0 = ssrc[i];
            float nrm = rsqrtf(fmaxf((float)odeg[s0], 1.0f));
            float2 v = ((const float2*)h)[(size_t)s0 * (NDIM / 2) + lane];
            a0 += v.x * nrm;
            a1 += v.y * nrm;
        }
        float2 o; o.x = a0; o.y = a1;
        ((float2*)agg)[(size_t)d * (NDIM / 2) + lane] = o;
    }
}

__global__ __launch_bounds__(256) void k_gemm_f32(float* __restrict__ io,
                                                  const float* __restrict__ W,
                                                  const float* __restrict__ bias,
                                                  const int* __restrict__ ideg, int M) {
    __shared__ float Wsf[NDIM][NDIM];
    int tx = threadIdx.x;
    {
        const float4* Wv = (const float4*)W;
        float4* Wsv = (float4*)&Wsf[0][0];
        for (int i = tx; i < NDIM * NDIM / 4; i += 256) Wsv[i] = Wv[i];
    }
    __syncthreads();
    int cg = tx & 31, rg = tx >> 5;
    int r0 = blockIdx.x * 64 + rg * 8, c0 = cg * 4;
    float acc[8][4];
#pragma unroll
    for (int r = 0; r < 8; ++r)
#pragma unroll
        for (int c = 0; c < 4; ++c) acc[r][c] = 0.f;
    for (int k4 = 0; k4 < NDIM / 4; ++k4) {
        float4 wk0 = *(const float4*)&Wsf[4 * k4 + 0][c0];
        float4 wk1 = *(const float4*)&Wsf[4 * k4 + 1][c0];
        float4 wk2 = *(const float4*)&Wsf[4 * k4 + 2][c0];
        float4 wk3 = *(const float4*)&Wsf[4 * k4 + 3][c0];
#pragma unroll
        for (int r = 0; r < 8; ++r) {
            int row = r0 + r;
            if (row < M) {
                float4 a = ((const float4*)io)[(size_t)row * (NDIM / 4) + k4];
                acc[r][0] += a.x * wk0.x + a.y * wk1.x + a.z * wk2.x + a.w * wk3.x;
                acc[r][1] += a.x * wk0.y + a.y * wk1.y + a.z * wk2.y + a.w * wk3.y;
                acc[r][2] += a.x * wk0.z + a.y * wk1.z + a.z * wk2.z + a.w * wk3.z;
                acc[r][3] += a.x * wk0.w + a.y * wk1.w + a.z * wk2.w + a.w * wk3.w;
            }
        }
    }
    __syncthreads();
    float4 b = *(const float4*)&bias[c0];
#pragma unroll
    for (int r = 0; r < 8; ++r) {
        int row = r0 + r;
        if (row < M) {
            float nrm = rsqrtf(fminf(fmaxf((float)ideg[row], 1.0f), KCLAMP));
            float4 o;
            o.x = acc[r][0] * nrm + b.x;
            o.y = acc[r][1] * nrm + b.y;
            o.z = acc[r][2] * nrm + b.z;
            o.w = acc[r][3] * nrm + b.w;
            ((float4*)io)[(size_t)row * (NDIM / 4) + cg] = o;
        }
    }
}

extern "C" void kernel_launch(void* const* d_in, const int* in_sizes, int n_in,
                              void* d_out, int out_size, void* d_ws, size_t ws_size,
                              hipStream_t stream) {
    const float* h_src  = (const float*)d_in[0];
    const float* weight = (const float*)d_in[1];
    const float* bias   = (const float*)d_in[2];
    const int*   ssrc   = (const int*)d_in[3];
    const int*   sdst   = (const int*)d_in[4];
    const int*   odeg   = (const int*)d_in[5];
    const int*   ideg   = (const int*)d_in[6];
    float* out = (float*)d_out;

    int E    = in_sizes[3];
    int nsrc = in_sizes[0] / NDIM;
    int ndst = out_size / NDIM;

    // ws layout: [0,1MB) row_start ; [1MB,1MB+32KB) wfrag ; [2MB, ..) trans
    int*      row_start = (int*)d_ws;
    uint16_t* wfrag = (uint16_t*)((char*)d_ws + ((size_t)1 << 20));
    uint16_t* trans = (uint16_t*)((char*)d_ws + ((size_t)2 << 20));
    size_t need = ((size_t)2 << 20) + (size_t)nsrc * NDIM * 2;

    if (ws_size >= need) {
        int wfBlocks = (NDIM * NDIM + 255) / 256;
        int rpBlocks = (ndst + 1 + 255) / 256;
        k_prep<<<wfBlocks + rpBlocks, 256, 0, stream>>>(
            weight, wfrag, sdst, E, row_start, ndst, wfBlocks);
        k1_gemm<<<(nsrc + 63) / 64, 256, 0, stream>>>(h_src, odeg, wfrag, trans,
                                                      nsrc, nsrc);
        int CPB = 256;                       // chunks per slice; grid 2048 fully resident
        int DPB = (ndst + CPB - 1) / CPB;
        k2_gather<<<8 * CPB, 256, 0, stream>>>(trans, ssrc, row_start, bias, ideg,
                                               out, ndst, nsrc, DPB);
    } else {
        k_rowptr<<<(ndst + 1 + 255) / 256, 256, 0, stream>>>(sdst, E, row_start, ndst);
        k_agg_f32<<<2048, 256, 0, stream>>>(h_src, odeg, ssrc, row_start, out, ndst);
        k_gemm_f32<<<(ndst + 63) / 64, 256, 0, stream>>>(out, weight, bias, ideg, ndst);
    }
}

// Round 10
// 74.452 us; speedup vs baseline: 2.0874x; 2.0874x over previous
//
#include <hip/hip_runtime.h>
#include <hip/hip_bf16.h>
#include <cstdint>

#define NDIM 128
#define KCLAMP 10.0f

using bf16x8 = __attribute__((ext_vector_type(8))) short;
using f32x4  = __attribute__((ext_vector_type(4))) float;
using f32x2  = __attribute__((ext_vector_type(2))) float;

__device__ __forceinline__ uint16_t f2bf(float f) {
    uint32_t u = __float_as_uint(f);
    uint32_t r = (u + 0x7fffu + ((u >> 16) & 1u)) >> 16;   // RNE
    return (uint16_t)r;
}
__device__ __forceinline__ float bf_lo(uint32_t v) { return __uint_as_float(v << 16); }
__device__ __forceinline__ float bf_hi(uint32_t v) { return __uint_as_float(v & 0xffff0000u); }

// ---------------- prep: wfrag only (64 blocks) ----------------
// wfrag[((n*4+s)*64+lane)*8+i] = bf16(W[k][col]), k=s*32+8*(lane>>4)+i, col=n*16+(lane&15)
__global__ void k_prep(const float* __restrict__ W, uint16_t* __restrict__ wfrag) {
    int t = blockIdx.x * 256 + threadIdx.x;
    if (t >= NDIM * NDIM) return;
    int i    = t & 7;
    int lane = (t >> 3) & 63;
    int s    = (t >> 9) & 3;
    int n    = t >> 11;
    int k    = s * 32 + 8 * (lane >> 4) + i;
    int col  = n * 16 + (lane & 15);
    wfrag[t] = f2bf(W[k * NDIM + col]);
}

// ---------------- k1: trans = bf16((h * norm_src) @ W)  +  rowptr role ----------------
// GEMM blocks [0, gemmBlocks): 256 thr = 4 waves, 64 rows/block; W frags from
// precomputed wfrag (coalesced int4 -> 32KB LDS); A-fragments straight from
// global f32 h, scaled, converted in-register. rowptr blocks follow.
__global__ __launch_bounds__(256) void k1_gemm(
        const float* __restrict__ h, const int* __restrict__ odeg,
        const uint16_t* __restrict__ wfrag, uint16_t* __restrict__ trans, int M,
        const int* __restrict__ sdst, int E, int* __restrict__ row_start, int ndst,
        int gemmBlocks) {
    int b = blockIdx.x;
    int tx = threadIdx.x;

    if (b >= gemmBlocks) {                 // ---- rowptr role ----
        int d = (b - gemmBlocks) * 256 + tx;
        if (d > ndst) return;
        int lo = 0, hi = E;
        while (lo < hi) {
            int mid = (lo + hi) >> 1;
            if (sdst[mid] < d) lo = mid + 1; else hi = mid;
        }
        row_start[d] = lo;
        return;
    }

    __shared__ uint16_t Ws[NDIM * NDIM];     // 32 KB, B-frag layout
    for (int i = tx; i < NDIM * NDIM / 8; i += 256)
        ((int4*)Ws)[i] = ((const int4*)wfrag)[i];
    __syncthreads();

    int wave = tx >> 6, lane = tx & 63;
    int g = lane >> 4;
    int r0 = b * 64 + wave * 16;
    int arow = r0 + (lane & 15);
    if (arow >= M) arow = M - 1;             // clamp loads; stores predicated
    float nrm = rsqrtf(fmaxf((float)odeg[arow], 1.0f));
    const float4* Arow = (const float4*)(h + (size_t)arow * NDIM);

    f32x4 acc[8];
#pragma unroll
    for (int n = 0; n < 8; ++n) acc[n] = (f32x4){0.f, 0.f, 0.f, 0.f};

#pragma unroll
    for (int s = 0; s < 4; ++s) {
        float4 a0 = Arow[s * 8 + g * 2];     // k = s*32+g*8 .. +3
        float4 a1 = Arow[s * 8 + g * 2 + 1]; // k = s*32+g*8+4 .. +7
        bf16x8 af;
        af[0] = (short)f2bf(a0.x * nrm);
        af[1] = (short)f2bf(a0.y * nrm);
        af[2] = (short)f2bf(a0.z * nrm);
        af[3] = (short)f2bf(a0.w * nrm);
        af[4] = (short)f2bf(a1.x * nrm);
        af[5] = (short)f2bf(a1.y * nrm);
        af[6] = (short)f2bf(a1.z * nrm);
        af[7] = (short)f2bf(a1.w * nrm);
#pragma unroll
        for (int n = 0; n < 8; ++n) {
            bf16x8 bfr = *(const bf16x8*)(Ws + (((n * 4 + s) * 64 + lane) << 3));
            acc[n] = __builtin_amdgcn_mfma_f32_16x16x32_bf16(af, bfr, acc[n], 0, 0, 0);
        }
    }

    int colL = lane & 15;
    int rowbase = r0 + g * 4;
#pragma unroll
    for (int n = 0; n < 8; ++n) {
#pragma unroll
        for (int r = 0; r < 4; ++r) {
            int row = rowbase + r;
            if (row < M)
                trans[(size_t)row * NDIM + n * 16 + colL] = f2bf(acc[n][r]);
        }
    }
}

// ---------------- k2: pure gather + segment-sum + epilogue (round-7 proven) ----------------
// 4 dst segments per wave (one per 16-lane slot), 8-deep clamped load pipeline.
// out[d] = (sum trans[src]) * rsqrt(clamp(ideg,1,K)) + bias
__global__ __launch_bounds__(256) void k2_gather(
        const uint16_t* __restrict__ trans,
        const int* __restrict__ ssrc, const int* __restrict__ row_start,
        const float* __restrict__ bias, const int* __restrict__ ideg,
        float* __restrict__ out, int ndst) {
    constexpr int U = 8;
    int gtid = blockIdx.x * blockDim.x + threadIdx.x;
    int wave = gtid >> 6;
    int lane = threadIdx.x & 63;
    int sub  = lane >> 4;          // dst slot 0..3
    int li   = lane & 15;          // 16B chunk within row
    int nwaves = (gridDim.x * blockDim.x) >> 6;

    float4 b0 = ((const float4*)bias)[li * 2];
    float4 b1 = ((const float4*)bias)[li * 2 + 1];

    for (int d0 = wave * 4; d0 < ndst; d0 += nwaves * 4) {
        int d = d0 + sub;
        int valid = (d < ndst);
        int s = 0, e = 0;
        if (valid) { s = row_start[d]; e = row_start[d + 1]; }
        int elast = (e > s) ? (e - 1) : 0;

        f32x2 acc[4];
#pragma unroll
        for (int k = 0; k < 4; ++k) acc[k] = (f32x2){0.f, 0.f};

        int idxv[U];
#pragma unroll
        for (int u = 0; u < U; ++u) idxv[u] = ssrc[min(s + u, elast)];

        int pos = s;
        while (__any(pos < e)) {
            uint4 v[U];
#pragma unroll
            for (int u = 0; u < U; ++u)
                v[u] = *(const uint4*)(trans + (size_t)idxv[u] * NDIM + li * 8);

            int npos = pos + U;
#pragma unroll
            for (int u = 0; u < U; ++u) idxv[u] = ssrc[min(npos + u, elast)];

#pragma unroll
            for (int u = 0; u < U; ++u) {
                if (pos + u < e) {
                    f32x2 t0 = {bf_lo(v[u].x), bf_hi(v[u].x)};
                    f32x2 t1 = {bf_lo(v[u].y), bf_hi(v[u].y)};
                    f32x2 t2 = {bf_lo(v[u].z), bf_hi(v[u].z)};
                    f32x2 t3 = {bf_lo(v[u].w), bf_hi(v[u].w)};
                    acc[0] += t0; acc[1] += t1; acc[2] += t2; acc[3] += t3;
                }
            }
            pos = npos;
        }

        if (valid) {
            float nrm = rsqrtf(fminf(fmaxf((float)ideg[d], 1.0f), KCLAMP));
            float4 o0, o1;
            o0.x = acc[0][0] * nrm + b0.x;
            o0.y = acc[0][1] * nrm + b0.y;
            o0.z = acc[1][0] * nrm + b0.z;
            o0.w = acc[1][1] * nrm + b0.w;
            o1.x = acc[2][0] * nrm + b1.x;
            o1.y = acc[2][1] * nrm + b1.y;
            o1.z = acc[3][0] * nrm + b1.z;
            o1.w = acc[3][1] * nrm + b1.w;
            ((float4*)out)[(size_t)d * (NDIM / 4) + li * 2]     = o0;
            ((float4*)out)[(size_t)d * (NDIM / 4) + li * 2 + 1] = o1;
        }
    }
}

// ---------------- fallbacks (workspace too small) ----------------
__global__ void k_rowptr(const int* __restrict__ sdst, int E,
                         int* __restrict__ row_start, int ndst) {
    int d = blockIdx.x * blockDim.x + threadIdx.x;
    if (d > ndst) return;
    int lo = 0, hi = E;
    while (lo < hi) {
        int mid = (lo + hi) >> 1;
        if (sdst[mid] < d) lo = mid + 1; else hi = mid;
    }
    row_start[d] = lo;
}

__global__ void k_agg_f32(const float* __restrict__ h, const int* __restrict__ odeg,
                          const int* __restrict__ ssrc, const int* __restrict__ row_start,
                          float* __restrict__ agg, int ndst) {
    int gtid = blockIdx.x * blockDim.x + threadIdx.x;
    int wave = gtid >> 6;
    int lane = threadIdx.x & 63;
    int nwaves = (gridDim.x * blockDim.x) >> 6;
    for (int d = wave; d < ndst; d += nwaves) {
        int s = row_start[d], e = row_start[d + 1];
        float a0 = 0.f, a1 = 0.f;
        for (int i = s; i < e; i++) {
            int s0 = ssrc[i];
            float nrm = rsqrtf(fmaxf((float)odeg[s0], 1.0f));
            float2 v = ((const float2*)h)[(size_t)s0 * (NDIM / 2) + lane];
            a0 += v.x * nrm;
            a1 += v.y * nrm;
        }
        float2 o; o.x = a0; o.y = a1;
        ((float2*)agg)[(size_t)d * (NDIM / 2) + lane] = o;
    }
}

__global__ __launch_bounds__(256) void k_gemm_f32(float* __restrict__ io,
                                                  const float* __restrict__ W,
                                                  const float* __restrict__ bias,
                                                  const int* __restrict__ ideg, int M) {
    __shared__ float Wsf[NDIM][NDIM];
    int tx = threadIdx.x;
    {
        const float4* Wv = (const float4*)W;
        float4* Wsv = (float4*)&Wsf[0][0];
        for (int i = tx; i < NDIM * NDIM / 4; i += 256) Wsv[i] = Wv[i];
    }
    __syncthreads();
    int cg = tx & 31, rg = tx >> 5;
    int r0 = blockIdx.x * 64 + rg * 8, c0 = cg * 4;
    float acc[8][4];
#pragma unroll
    for (int r = 0; r < 8; ++r)
#pragma unroll
        for (int c = 0; c < 4; ++c) acc[r][c] = 0.f;
    for (int k4 = 0; k4 < NDIM / 4; ++k4) {
        float4 wk0 = *(const float4*)&Wsf[4 * k4 + 0][c0];
        float4 wk1 = *(const float4*)&Wsf[4 * k4 + 1][c0];
        float4 wk2 = *(const float4*)&Wsf[4 * k4 + 2][c0];
        float4 wk3 = *(const float4*)&Wsf[4 * k4 + 3][c0];
#pragma unroll
        for (int r = 0; r < 8; ++r) {
            int row = r0 + r;
            if (row < M) {
                float4 a = ((const float4*)io)[(size_t)row * (NDIM / 4) + k4];
                acc[r][0] += a.x * wk0.x + a.y * wk1.x + a.z * wk2.x + a.w * wk3.x;
                acc[r][1] += a.x * wk0.y + a.y * wk1.y + a.z * wk2.y + a.w * wk3.y;
                acc[r][2] += a.x * wk0.z + a.y * wk1.z + a.z * wk2.z + a.w * wk3.z;
                acc[r][3] += a.x * wk0.w + a.y * wk1.w + a.z * wk2.w + a.w * wk3.w;
            }
        }
    }
    __syncthreads();
    float4 b = *(const float4*)&bias[c0];
#pragma unroll
    for (int r = 0; r < 8; ++r) {
        int row = r0 + r;
        if (row < M) {
            float nrm = rsqrtf(fminf(fmaxf((float)ideg[row], 1.0f), KCLAMP));
            float4 o;
            o.x = acc[r][0] * nrm + b.x;
            o.y = acc[r][1] * nrm + b.y;
            o.z = acc[r][2] * nrm + b.z;
            o.w = acc[r][3] * nrm + b.w;
            ((float4*)io)[(size_t)row * (NDIM / 4) + cg] = o;
        }
    }
}

extern "C" void kernel_launch(void* const* d_in, const int* in_sizes, int n_in,
                              void* d_out, int out_size, void* d_ws, size_t ws_size,
                              hipStream_t stream) {
    const float* h_src  = (const float*)d_in[0];
    const float* weight = (const float*)d_in[1];
    const float* bias   = (const float*)d_in[2];
    const int*   ssrc   = (const int*)d_in[3];
    const int*   sdst   = (const int*)d_in[4];
    const int*   odeg   = (const int*)d_in[5];
    const int*   ideg   = (const int*)d_in[6];
    float* out = (float*)d_out;

    int E    = in_sizes[3];
    int nsrc = in_sizes[0] / NDIM;
    int ndst = out_size / NDIM;

    // ws layout: [0,1MB) row_start ; [1MB,1MB+32KB) wfrag ; [2MB, ..) trans
    int*      row_start = (int*)d_ws;
    uint16_t* wfrag = (uint16_t*)((char*)d_ws + ((size_t)1 << 20));
    uint16_t* trans = (uint16_t*)((char*)d_ws + ((size_t)2 << 20));
    size_t need = ((size_t)2 << 20) + (size_t)nsrc * NDIM * 2;

    if (ws_size >= need) {
        int wfBlocks   = (NDIM * NDIM + 255) / 256;
        int gemmBlocks = (nsrc + 63) / 64;
        int rpBlocks   = (ndst + 1 + 255) / 256;
        k_prep<<<wfBlocks, 256, 0, stream>>>(weight, wfrag);
        k1_gemm<<<gemmBlocks + rpBlocks, 256, 0, stream>>>(
            h_src, odeg, wfrag, trans, nsrc, sdst, E, row_start, ndst, gemmBlocks);
        k2_gather<<<2048, 256, 0, stream>>>(trans, ssrc, row_start, bias, ideg, out, ndst);
    } else {
        k_rowptr<<<(ndst + 1 + 255) / 256, 256, 0, stream>>>(sdst, E, row_start, ndst);
        k_agg_f32<<<2048, 256, 0, stream>>>(h_src, odeg, ssrc, row_start, out, ndst);
        k_gemm_f32<<<(ndst + 63) / 64, 256, 0, stream>>>(out, weight, bias, ideg, ndst);
    }
}

// Round 11
// 73.188 us; speedup vs baseline: 2.1234x; 1.0173x over previous
//
#include <hip/hip_runtime.h>
#include <hip/hip_bf16.h>
#include <cstdint>

#define NDIM 128
#define KCLAMP 10.0f

using bf16x8 = __attribute__((ext_vector_type(8))) short;
using f32x4  = __attribute__((ext_vector_type(4))) float;
using f32x2  = __attribute__((ext_vector_type(2))) float;

__device__ __forceinline__ uint16_t f2bf(float f) {
    uint32_t u = __float_as_uint(f);
    uint32_t r = (u + 0x7fffu + ((u >> 16) & 1u)) >> 16;   // RNE
    return (uint16_t)r;
}
__device__ __forceinline__ float bf_lo(uint32_t v) { return __uint_as_float(v << 16); }
__device__ __forceinline__ float bf_hi(uint32_t v) { return __uint_as_float(v & 0xffff0000u); }

// ---------------- k1: trans = bf16((h * norm_src) @ W)  +  rowptr role ----------------
// GEMM blocks [0, gemmBlocks): 512 thr = 8 waves, 128 rows/block.
// Each block stages W itself: coalesced float4 reads of row-major W, transpose-
// scatter into the MFMA B-frag LDS layout (u16 writes, 64B lane stride -> 2-way
// bank aliasing = free). A-fragments straight from global f32 h. rowptr after.
__global__ __launch_bounds__(512) void k1_gemm(
        const float* __restrict__ h, const int* __restrict__ odeg,
        const float* __restrict__ W, uint16_t* __restrict__ trans, int M,
        const int* __restrict__ sdst, int E, int* __restrict__ row_start, int ndst,
        int gemmBlocks) {
    int b = blockIdx.x;
    int tx = threadIdx.x;

    if (b >= gemmBlocks) {                 // ---- rowptr role ----
        int d = (b - gemmBlocks) * 512 + tx;
        if (d > ndst) return;
        int lo = 0, hi = E;
        while (lo < hi) {
            int mid = (lo + hi) >> 1;
            if (sdst[mid] < d) lo = mid + 1; else hi = mid;
        }
        row_start[d] = lo;
        return;
    }

    __shared__ uint16_t Ws[NDIM * NDIM];     // 32 KB, B-frag layout
    // stage W: Ws[((n*4+s)*64 + lh*16 + ll)*8 + i] = bf16(W[r][c]),
    //          r = s*32 + lh*8 + i, c = n*16 + ll
    for (int j = tx; j < NDIM * NDIM / 4; j += 512) {
        float4 w4 = ((const float4*)W)[j];
        int r  = j >> 5;
        int c4 = (j & 31) * 4;
        int s  = r >> 5, lh = (r >> 3) & 3, i = r & 7;
        int base_s = s, base_i = i;
#pragma unroll
        for (int q = 0; q < 4; ++q) {
            int c = c4 + q;
            int n = c >> 4, ll = c & 15;
            int off = ((n * 4 + base_s) * 64 + lh * 16 + ll) * 8 + base_i;
            float val = (q == 0) ? w4.x : (q == 1) ? w4.y : (q == 2) ? w4.z : w4.w;
            Ws[off] = f2bf(val);
        }
    }
    __syncthreads();

    int wave = tx >> 6, lane = tx & 63;
    int g = lane >> 4;
    int r0 = b * 128 + wave * 16;
    int arow = r0 + (lane & 15);
    if (arow >= M) arow = M - 1;             // clamp loads; stores predicated
    float nrm = rsqrtf(fmaxf((float)odeg[arow], 1.0f));
    const float4* Arow = (const float4*)(h + (size_t)arow * NDIM);

    f32x4 acc[8];
#pragma unroll
    for (int n = 0; n < 8; ++n) acc[n] = (f32x4){0.f, 0.f, 0.f, 0.f};

#pragma unroll
    for (int s = 0; s < 4; ++s) {
        float4 a0 = Arow[s * 8 + g * 2];     // k = s*32+g*8 .. +3
        float4 a1 = Arow[s * 8 + g * 2 + 1]; // k = s*32+g*8+4 .. +7
        bf16x8 af;
        af[0] = (short)f2bf(a0.x * nrm);
        af[1] = (short)f2bf(a0.y * nrm);
        af[2] = (short)f2bf(a0.z * nrm);
        af[3] = (short)f2bf(a0.w * nrm);
        af[4] = (short)f2bf(a1.x * nrm);
        af[5] = (short)f2bf(a1.y * nrm);
        af[6] = (short)f2bf(a1.z * nrm);
        af[7] = (short)f2bf(a1.w * nrm);
#pragma unroll
        for (int n = 0; n < 8; ++n) {
            bf16x8 bfr = *(const bf16x8*)(Ws + (((n * 4 + s) * 64 + lane) << 3));
            acc[n] = __builtin_amdgcn_mfma_f32_16x16x32_bf16(af, bfr, acc[n], 0, 0, 0);
        }
    }

    int colL = lane & 15;
    int rowbase = r0 + g * 4;
#pragma unroll
    for (int n = 0; n < 8; ++n) {
#pragma unroll
        for (int r = 0; r < 4; ++r) {
            int row = rowbase + r;
            if (row < M)
                trans[(size_t)row * NDIM + n * 16 + colL] = f2bf(acc[n][r]);
        }
    }
}

// ---------------- k2: pure gather + segment-sum + epilogue (round-7/10 proven) ----------------
// 4 dst segments per wave (one per 16-lane slot), 8-deep clamped load pipeline.
// out[d] = (sum trans[src]) * rsqrt(clamp(ideg,1,K)) + bias
__global__ __launch_bounds__(256) void k2_gather(
        const uint16_t* __restrict__ trans,
        const int* __restrict__ ssrc, const int* __restrict__ row_start,
        const float* __restrict__ bias, const int* __restrict__ ideg,
        float* __restrict__ out, int ndst) {
    constexpr int U = 8;
    int gtid = blockIdx.x * blockDim.x + threadIdx.x;
    int wave = gtid >> 6;
    int lane = threadIdx.x & 63;
    int sub  = lane >> 4;          // dst slot 0..3
    int li   = lane & 15;          // 16B chunk within row
    int nwaves = (gridDim.x * blockDim.x) >> 6;

    float4 b0 = ((const float4*)bias)[li * 2];
    float4 b1 = ((const float4*)bias)[li * 2 + 1];

    for (int d0 = wave * 4; d0 < ndst; d0 += nwaves * 4) {
        int d = d0 + sub;
        int valid = (d < ndst);
        int s = 0, e = 0;
        if (valid) { s = row_start[d]; e = row_start[d + 1]; }
        int elast = (e > s) ? (e - 1) : 0;

        f32x2 acc[4];
#pragma unroll
        for (int k = 0; k < 4; ++k) acc[k] = (f32x2){0.f, 0.f};

        int idxv[U];
#pragma unroll
        for (int u = 0; u < U; ++u) idxv[u] = ssrc[min(s + u, elast)];

        int pos = s;
        while (__any(pos < e)) {
            uint4 v[U];
#pragma unroll
            for (int u = 0; u < U; ++u)
                v[u] = *(const uint4*)(trans + (size_t)idxv[u] * NDIM + li * 8);

            int npos = pos + U;
#pragma unroll
            for (int u = 0; u < U; ++u) idxv[u] = ssrc[min(npos + u, elast)];

#pragma unroll
            for (int u = 0; u < U; ++u) {
                if (pos + u < e) {
                    f32x2 t0 = {bf_lo(v[u].x), bf_hi(v[u].x)};
                    f32x2 t1 = {bf_lo(v[u].y), bf_hi(v[u].y)};
                    f32x2 t2 = {bf_lo(v[u].z), bf_hi(v[u].z)};
                    f32x2 t3 = {bf_lo(v[u].w), bf_hi(v[u].w)};
                    acc[0] += t0; acc[1] += t1; acc[2] += t2; acc[3] += t3;
                }
            }
            pos = npos;
        }

        if (valid) {
            float nrm = rsqrtf(fminf(fmaxf((float)ideg[d], 1.0f), KCLAMP));
            float4 o0, o1;
            o0.x = acc[0][0] * nrm + b0.x;
            o0.y = acc[0][1] * nrm + b0.y;
            o0.z = acc[1][0] * nrm + b0.z;
            o0.w = acc[1][1] * nrm + b0.w;
            o1.x = acc[2][0] * nrm + b1.x;
            o1.y = acc[2][1] * nrm + b1.y;
            o1.z = acc[3][0] * nrm + b1.z;
            o1.w = acc[3][1] * nrm + b1.w;
            ((float4*)out)[(size_t)d * (NDIM / 4) + li * 2]     = o0;
            ((float4*)out)[(size_t)d * (NDIM / 4) + li * 2 + 1] = o1;
        }
    }
}

// ---------------- fallbacks (workspace too small) ----------------
__global__ void k_rowptr(const int* __restrict__ sdst, int E,
                         int* __restrict__ row_start, int ndst) {
    int d = blockIdx.x * blockDim.x + threadIdx.x;
    if (d > ndst) return;
    int lo = 0, hi = E;
    while (lo < hi) {
        int mid = (lo + hi) >> 1;
        if (sdst[mid] < d) lo = mid + 1; else hi = mid;
    }
    row_start[d] = lo;
}

__global__ void k_agg_f32(const float* __restrict__ h, const int* __restrict__ odeg,
                          const int* __restrict__ ssrc, const int* __restrict__ row_start,
                          float* __restrict__ agg, int ndst) {
    int gtid = blockIdx.x * blockDim.x + threadIdx.x;
    int wave = gtid >> 6;
    int lane = threadIdx.x & 63;
    int nwaves = (gridDim.x * blockDim.x) >> 6;
    for (int d = wave; d < ndst; d += nwaves) {
        int s = row_start[d], e = row_start[d + 1];
        float a0 = 0.f, a1 = 0.f;
        for (int i = s; i < e; i++) {
            int s0 = ssrc[i];
            float nrm = rsqrtf(fmaxf((float)odeg[s0], 1.0f));
            float2 v = ((const float2*)h)[(size_t)s0 * (NDIM / 2) + lane];
            a0 += v.x * nrm;
            a1 += v.y * nrm;
        }
        float2 o; o.x = a0; o.y = a1;
        ((float2*)agg)[(size_t)d * (NDIM / 2) + lane] = o;
    }
}

__global__ __launch_bounds__(256) void k_gemm_f32(float* __restrict__ io,
                                                  const float* __restrict__ W,
                                                  const float* __restrict__ bias,
                                                  const int* __restrict__ ideg, int M) {
    __shared__ float Wsf[NDIM][NDIM];
    int tx = threadIdx.x;
    {
        const float4* Wv = (const float4*)W;
        float4* Wsv = (float4*)&Wsf[0][0];
        for (int i = tx; i < NDIM * NDIM / 4; i += 256) Wsv[i] = Wv[i];
    }
    __syncthreads();
    int cg = tx & 31, rg = tx >> 5;
    int r0 = blockIdx.x * 64 + rg * 8, c0 = cg * 4;
    float acc[8][4];
#pragma unroll
    for (int r = 0; r < 8; ++r)
#pragma unroll
        for (int c = 0; c < 4; ++c) acc[r][c] = 0.f;
    for (int k4 = 0; k4 < NDIM / 4; ++k4) {
        float4 wk0 = *(const float4*)&Wsf[4 * k4 + 0][c0];
        float4 wk1 = *(const float4*)&Wsf[4 * k4 + 1][c0];
        float4 wk2 = *(const float4*)&Wsf[4 * k4 + 2][c0];
        float4 wk3 = *(const float4*)&Wsf[4 * k4 + 3][c0];
#pragma unroll
        for (int r = 0; r < 8; ++r) {
            int row = r0 + r;
            if (row < M) {
                float4 a = ((const float4*)io)[(size_t)row * (NDIM / 4) + k4];
                acc[r][0] += a.x * wk0.x + a.y * wk1.x + a.z * wk2.x + a.w * wk3.x;
                acc[r][1] += a.x * wk0.y + a.y * wk1.y + a.z * wk2.y + a.w * wk3.y;
                acc[r][2] += a.x * wk0.z + a.y * wk1.z + a.z * wk2.z + a.w * wk3.z;
                acc[r][3] += a.x * wk0.w + a.y * wk1.w + a.z * wk2.w + a.w * wk3.w;
            }
        }
    }
    __syncthreads();
    float4 b = *(const float4*)&bias[c0];
#pragma unroll
    for (int r = 0; r < 8; ++r) {
        int row = r0 + r;
        if (row < M) {
            float nrm = rsqrtf(fminf(fmaxf((float)ideg[row], 1.0f), KCLAMP));
            float4 o;
            o.x = acc[r][0] * nrm + b.x;
            o.y = acc[r][1] * nrm + b.y;
            o.z = acc[r][2] * nrm + b.z;
            o.w = acc[r][3] * nrm + b.w;
            ((float4*)io)[(size_t)row * (NDIM / 4) + cg] = o;
        }
    }
}

extern "C" void kernel_launch(void* const* d_in, const int* in_sizes, int n_in,
                              void* d_out, int out_size, void* d_ws, size_t ws_size,
                              hipStream_t stream) {
    const float* h_src  = (const float*)d_in[0];
    const float* weight = (const float*)d_in[1];
    const float* bias   = (const float*)d_in[2];
    const int*   ssrc   = (const int*)d_in[3];
    const int*   sdst   = (const int*)d_in[4];
    const int*   odeg   = (const int*)d_in[5];
    const int*   ideg   = (const int*)d_in[6];
    float* out = (float*)d_out;

    int E    = in_sizes[3];
    int nsrc = in_sizes[0] / NDIM;
    int ndst = out_size / NDIM;

    // ws layout: [0,1MB) row_start ; [1MB, ..) trans (bf16 nsrc x 128)
    int*      row_start = (int*)d_ws;
    uint16_t* trans = (uint16_t*)((char*)d_ws + ((size_t)1 << 20));
    size_t need = ((size_t)1 << 20) + (size_t)nsrc * NDIM * 2;

    if (ws_size >= need) {
        int gemmBlocks = (nsrc + 127) / 128;
        int rpBlocks   = (ndst + 1 + 511) / 512;
        k1_gemm<<<gemmBlocks + rpBlocks, 512, 0, stream>>>(
            h_src, odeg, weight, trans, nsrc, sdst, E, row_start, ndst, gemmBlocks);
        k2_gather<<<2048, 256, 0, stream>>>(trans, ssrc, row_start, bias, ideg, out, ndst);
    } else {
        k_rowptr<<<(ndst + 1 + 255) / 256, 256, 0, stream>>>(sdst, E, row_start, ndst);
        k_agg_f32<<<2048, 256, 0, stream>>>(h_src, odeg, ssrc, row_start, out, ndst);
        k_gemm_f32<<<(ndst + 63) / 64, 256, 0, stream>>>(out, weight, bias, ideg, ndst);
    }
}